// Round 1
// baseline (1295.958 us; speedup 1.0000x reference)
//
#include <hip/hip_runtime.h>
#include <hip/hip_bf16.h>

#define N_NODES 50000
#define N_EDGES 800000
#define NHEAD 4
#define DHEAD 64
#define FDIM 256   // NHEAD*DHEAD == in_feats == out_feats

// ---------------- helpers ----------------
__device__ __forceinline__ unsigned fenc(float f) {
    unsigned b = __float_as_uint(f);
    return (b & 0x80000000u) ? ~b : (b | 0x80000000u);
}
__device__ __forceinline__ float fdec(unsigned k) {
    unsigned b = (k & 0x80000000u) ? (k & 0x7FFFFFFFu) : ~k;
    return __uint_as_float(b);
}

// ---------------- CSR build ----------------
__global__ void degree_kernel(const int* __restrict__ dst, int* __restrict__ cnt, int E) {
    int e = blockIdx.x * 256 + threadIdx.x;
    if (e < E) atomicAdd(&cnt[dst[e]], 1);
}

// single-block inclusive scan with carry; rowptr[0]=0, rowptr[i+1]=sum(cnt[0..i])
__global__ void scan_kernel(const int* __restrict__ cnt, int* __restrict__ rowptr, int N) {
    __shared__ int sdata[1024];
    __shared__ int carry_s;
    if (threadIdx.x == 0) { carry_s = 0; rowptr[0] = 0; }
    __syncthreads();
    for (int base = 0; base < N; base += 1024) {
        int i = base + (int)threadIdx.x;
        int v = (i < N) ? cnt[i] : 0;
        sdata[threadIdx.x] = v;
        __syncthreads();
        for (int off = 1; off < 1024; off <<= 1) {
            int t = (threadIdx.x >= (unsigned)off) ? sdata[threadIdx.x - off] : 0;
            __syncthreads();
            sdata[threadIdx.x] += t;
            __syncthreads();
        }
        int inc = sdata[threadIdx.x] + carry_s;
        if (i < N) rowptr[i + 1] = inc;
        __syncthreads();
        if (threadIdx.x == 1023) carry_s = inc;
        __syncthreads();
    }
}

__global__ void copy_kernel(const int* __restrict__ a, int* __restrict__ b, int N) {
    int i = blockIdx.x * 256 + threadIdx.x;
    if (i < N) b[i] = a[i];
}

__global__ void scatter_kernel(const int* __restrict__ dst, int* __restrict__ cursor,
                               int* __restrict__ eid, int E) {
    int e = blockIdx.x * 256 + threadIdx.x;
    if (e < E) {
        int pos = atomicAdd(&cursor[dst[e]], 1);
        eid[pos] = e;
    }
}

// ---------------- GEMM: C[M,256] = A[M,256] @ B[256,256], fp32 ----------------
#define TM 128
#define TN 128
#define TK 16
__global__ __launch_bounds__(256) void gemm_kernel(const float* __restrict__ A,
                                                   const float* __restrict__ B,
                                                   float* __restrict__ C, int M) {
    __shared__ float As[TK][TM + 4];
    __shared__ float Bs[TK][TN + 4];
    const int t = threadIdx.x;
    const int row0 = blockIdx.x * TM;
    const int col0 = blockIdx.y * TN;
    const int rm0 = (t >> 4) * 4;   // 0..60
    const int cn0 = (t & 15) * 4;   // 0..60

    float acc[8][8];
#pragma unroll
    for (int i = 0; i < 8; ++i)
#pragma unroll
        for (int j = 0; j < 8; ++j) acc[i][j] = 0.f;

    for (int kk = 0; kk < 256; kk += TK) {
        // A tile 128x16 -> As[k][m]
#pragma unroll
        for (int r = 0; r < 2; ++r) {
            int row = (t >> 2) + r * 64;      // 0..127
            int c4 = (t & 3) * 4;             // 0,4,8,12
            float4 v = make_float4(0.f, 0.f, 0.f, 0.f);
            int grow = row0 + row;
            if (grow < M) v = *reinterpret_cast<const float4*>(A + (size_t)grow * 256 + kk + c4);
            As[c4 + 0][row] = v.x;
            As[c4 + 1][row] = v.y;
            As[c4 + 2][row] = v.z;
            As[c4 + 3][row] = v.w;
        }
        // B tile 16x128 -> Bs[k][n]
#pragma unroll
        for (int r = 0; r < 2; ++r) {
            int k = (t >> 5) + r * 8;         // 0..15
            int c4 = (t & 31) * 4;            // 0..124
            float4 v = *reinterpret_cast<const float4*>(B + (size_t)(kk + k) * 256 + col0 + c4);
            *reinterpret_cast<float4*>(&Bs[k][c4]) = v;
        }
        __syncthreads();
#pragma unroll
        for (int k = 0; k < TK; ++k) {
            float4 a0 = *reinterpret_cast<const float4*>(&As[k][rm0]);
            float4 a1 = *reinterpret_cast<const float4*>(&As[k][rm0 + 64]);
            float4 b0 = *reinterpret_cast<const float4*>(&Bs[k][cn0]);
            float4 b1 = *reinterpret_cast<const float4*>(&Bs[k][cn0 + 64]);
            float av[8] = {a0.x, a0.y, a0.z, a0.w, a1.x, a1.y, a1.z, a1.w};
            float bv[8] = {b0.x, b0.y, b0.z, b0.w, b1.x, b1.y, b1.z, b1.w};
#pragma unroll
            for (int i = 0; i < 8; ++i)
#pragma unroll
                for (int j = 0; j < 8; ++j) acc[i][j] = fmaf(av[i], bv[j], acc[i][j]);
        }
        __syncthreads();
    }
#pragma unroll
    for (int i = 0; i < 8; ++i) {
        int lrow = (i < 4) ? (rm0 + i) : (rm0 + 64 + i - 4);
        int grow = row0 + lrow;
        if (grow >= M) continue;
        float4 v0 = make_float4(acc[i][0], acc[i][1], acc[i][2], acc[i][3]);
        float4 v1 = make_float4(acc[i][4], acc[i][5], acc[i][6], acc[i][7]);
        *reinterpret_cast<float4*>(C + (size_t)grow * 256 + col0 + cn0) = v0;
        *reinterpret_cast<float4*>(C + (size_t)grow * 256 + col0 + cn0 + 64) = v1;
    }
}

// ---------------- el/er: per-node head dots ----------------
__global__ void eler_kernel(const float* __restrict__ feat, const float* __restrict__ al,
                            const float* __restrict__ ar, float* __restrict__ el,
                            float* __restrict__ er, int N) {
    int node = blockIdx.x * 4 + (threadIdx.x >> 6);
    if (node >= N) return;
    int lane = threadIdx.x & 63;
    float4 f = *reinterpret_cast<const float4*>(feat + (size_t)node * FDIM + lane * 4);
    float4 a = *reinterpret_cast<const float4*>(al + lane * 4);
    float4 b = *reinterpret_cast<const float4*>(ar + lane * 4);
    float pl = f.x * a.x + f.y * a.y + f.z * a.z + f.w * a.w;
    float pr = f.x * b.x + f.y * b.y + f.z * b.z + f.w * b.w;
#pragma unroll
    for (int m = 1; m < 16; m <<= 1) {
        pl += __shfl_xor(pl, m, 64);
        pr += __shfl_xor(pr, m, 64);
    }
    if ((lane & 15) == 0) {
        int h = lane >> 4;
        el[node * NHEAD + h] = pl;
        er[node * NHEAD + h] = pr;
    }
}

// ---------------- edge pass 1: e = leaky_relu(el[src]+er[dst]); segment max ----------------
__global__ void edge1_kernel(const float* __restrict__ el, const float* __restrict__ er,
                             const int* __restrict__ src, const int* __restrict__ dst,
                             float* __restrict__ ebuf, unsigned* __restrict__ emax, int E) {
    int e = blockIdx.x * 256 + threadIdx.x;
    if (e >= E) return;
    int s = src[e], d = dst[e];
    float4 l = *reinterpret_cast<const float4*>(el + (size_t)s * NHEAD);
    float4 r = *reinterpret_cast<const float4*>(er + (size_t)d * NHEAD);
    float v[4] = {l.x + r.x, l.y + r.y, l.z + r.z, l.w + r.w};
    float4 o;
    float* op = &o.x;
#pragma unroll
    for (int h = 0; h < 4; ++h) {
        float x = v[h];
        x = x > 0.f ? x : 0.2f * x;
        op[h] = x;
        atomicMax(&emax[d * NHEAD + h], fenc(x));
    }
    *reinterpret_cast<float4*>(ebuf + (size_t)e * NHEAD) = o;
}

// ---------------- edge pass 2: ex = exp(e - emax[dst]); segment sum ----------------
__global__ void edge2_kernel(float* __restrict__ ebuf, const int* __restrict__ dst,
                             const unsigned* __restrict__ emax, float* __restrict__ den, int E) {
    int e = blockIdx.x * 256 + threadIdx.x;
    if (e >= E) return;
    int d = dst[e];
    float4 v = *reinterpret_cast<const float4*>(ebuf + (size_t)e * NHEAD);
    float ex0 = __expf(v.x - fdec(emax[d * NHEAD + 0]));
    float ex1 = __expf(v.y - fdec(emax[d * NHEAD + 1]));
    float ex2 = __expf(v.z - fdec(emax[d * NHEAD + 2]));
    float ex3 = __expf(v.w - fdec(emax[d * NHEAD + 3]));
    *reinterpret_cast<float4*>(ebuf + (size_t)e * NHEAD) = make_float4(ex0, ex1, ex2, ex3);
    atomicAdd(&den[d * NHEAD + 0], ex0);
    atomicAdd(&den[d * NHEAD + 1], ex1);
    atomicAdd(&den[d * NHEAD + 2], ex2);
    atomicAdd(&den[d * NHEAD + 3], ex3);
}

// ---------------- aggregation: one wave per dst node ----------------
__global__ void agg_kernel(const float* __restrict__ feat, const float* __restrict__ ebuf,
                           const float* __restrict__ den, const int* __restrict__ rowptr,
                           const int* __restrict__ eid, const int* __restrict__ src,
                           const float* __restrict__ resid, float* __restrict__ out, int N) {
    int node = blockIdx.x * 4 + (threadIdx.x >> 6);
    if (node >= N) return;
    int lane = threadIdx.x & 63;
    int head = lane >> 4;
    float d = den[node * NHEAD + head];
    float dinv = d > 0.f ? 1.0f / d : 0.f;
    float4 acc = make_float4(0.f, 0.f, 0.f, 0.f);
    int beg = rowptr[node], end = rowptr[node + 1];
    for (int p = beg; p < end; ++p) {
        int e = eid[p];
        int s = src[e];
        float w = ebuf[(size_t)e * NHEAD + head] * dinv;
        float4 f = *reinterpret_cast<const float4*>(feat + (size_t)s * FDIM + lane * 4);
        acc.x = fmaf(w, f.x, acc.x);
        acc.y = fmaf(w, f.y, acc.y);
        acc.z = fmaf(w, f.z, acc.z);
        acc.w = fmaf(w, f.w, acc.w);
    }
    if (resid) {
        float4 r = *reinterpret_cast<const float4*>(resid + (size_t)node * FDIM + lane * 4);
        acc.x += r.x; acc.y += r.y; acc.z += r.z; acc.w += r.w;
    }
    acc.x = acc.x > 0.f ? acc.x : expm1f(acc.x);
    acc.y = acc.y > 0.f ? acc.y : expm1f(acc.y);
    acc.z = acc.z > 0.f ? acc.z : expm1f(acc.z);
    acc.w = acc.w > 0.f ? acc.w : expm1f(acc.w);
    *reinterpret_cast<float4*>(out + (size_t)node * FDIM + lane * 4) = acc;
}

// ---------------- launch ----------------
extern "C" void kernel_launch(void* const* d_in, const int* in_sizes, int n_in,
                              void* d_out, int out_size, void* d_ws, size_t ws_size,
                              hipStream_t stream) {
    const float* features = (const float*)d_in[0];
    const int*   src      = (const int*)d_in[1];
    const int*   dst      = (const int*)d_in[2];
    const float* W1       = (const float*)d_in[3];
    const float* al1      = (const float*)d_in[4];
    const float* ar1      = (const float*)d_in[5];
    const float* W2       = (const float*)d_in[6];
    const float* al2      = (const float*)d_in[7];
    const float* ar2      = (const float*)d_in[8];
    float* out = (float*)d_out;

    const int N = N_NODES, E = N_EDGES;

    char* ws = (char*)d_ws;
    size_t off = 0;
    auto alloc = [&](size_t bytes) -> void* {
        void* p = ws + off;
        off = (off + bytes + 255) & ~(size_t)255;
        return p;
    };
    float*    feat   = (float*)alloc((size_t)N * FDIM * 4);
    float*    h2     = (float*)alloc((size_t)N * FDIM * 4);
    float*    ebuf   = (float*)alloc((size_t)E * NHEAD * 4);
    float*    el     = (float*)alloc((size_t)N * NHEAD * 4);
    float*    er     = (float*)alloc((size_t)N * NHEAD * 4);
    unsigned* emax   = (unsigned*)alloc((size_t)N * NHEAD * 4);
    float*    den    = (float*)alloc((size_t)N * NHEAD * 4);
    int*      rowptr = (int*)alloc((size_t)(N + 1) * 4);
    int*      cursor = (int*)alloc((size_t)N * 4);
    int*      eid    = (int*)alloc((size_t)E * 4);

    const int egrid = (E + 255) / 256;
    const int ngrid4 = (N + 3) / 4;

    // ---- CSR build (by dst) ----
    hipMemsetAsync(cursor, 0, (size_t)N * 4, stream);
    degree_kernel<<<egrid, 256, 0, stream>>>(dst, cursor, E);
    scan_kernel<<<1, 1024, 0, stream>>>(cursor, rowptr, N);
    copy_kernel<<<(N + 255) / 256, 256, 0, stream>>>(rowptr, cursor, N);
    scatter_kernel<<<egrid, 256, 0, stream>>>(dst, cursor, eid, E);

    dim3 ggrid((N + TM - 1) / TM, FDIM / TN);

    // ---- layer 1 ----
    gemm_kernel<<<ggrid, 256, 0, stream>>>(features, W1, feat, N);
    eler_kernel<<<ngrid4, 256, 0, stream>>>(feat, al1, ar1, el, er, N);
    hipMemsetAsync(emax, 0, (size_t)N * NHEAD * 4, stream);
    hipMemsetAsync(den, 0, (size_t)N * NHEAD * 4, stream);
    edge1_kernel<<<egrid, 256, 0, stream>>>(el, er, src, dst, ebuf, emax, E);
    edge2_kernel<<<egrid, 256, 0, stream>>>(ebuf, dst, emax, den, E);
    agg_kernel<<<ngrid4, 256, 0, stream>>>(feat, ebuf, den, rowptr, eid, src, nullptr, h2, N);

    // ---- layer 2 (residual) ----
    gemm_kernel<<<ggrid, 256, 0, stream>>>(h2, W2, feat, N);
    eler_kernel<<<ngrid4, 256, 0, stream>>>(feat, al2, ar2, el, er, N);
    hipMemsetAsync(emax, 0, (size_t)N * NHEAD * 4, stream);
    hipMemsetAsync(den, 0, (size_t)N * NHEAD * 4, stream);
    edge1_kernel<<<egrid, 256, 0, stream>>>(el, er, src, dst, ebuf, emax, E);
    edge2_kernel<<<egrid, 256, 0, stream>>>(ebuf, dst, emax, den, E);
    agg_kernel<<<ngrid4, 256, 0, stream>>>(feat, ebuf, den, rowptr, eid, src, h2, out, N);
}

// Round 2
// 653.741 us; speedup vs baseline: 1.9824x; 1.9824x over previous
//
#include <hip/hip_runtime.h>
#include <hip/hip_bf16.h>

#define N_NODES 50000
#define N_EDGES 800000
#define NHEAD 4
#define DHEAD 64
#define FDIM 256   // NHEAD*DHEAD == in_feats == out_feats

// ---------------- CSR build ----------------
__global__ void degree_kernel(const int* __restrict__ dst, int* __restrict__ cnt, int E) {
    int e = blockIdx.x * 256 + threadIdx.x;
    if (e < E) atomicAdd(&cnt[dst[e]], 1);
}

// single-block inclusive scan with carry; rowptr[0]=0, rowptr[i+1]=sum(cnt[0..i])
__global__ void scan_kernel(const int* __restrict__ cnt, int* __restrict__ rowptr, int N) {
    __shared__ int sdata[1024];
    __shared__ int carry_s;
    if (threadIdx.x == 0) { carry_s = 0; rowptr[0] = 0; }
    __syncthreads();
    for (int base = 0; base < N; base += 1024) {
        int i = base + (int)threadIdx.x;
        int v = (i < N) ? cnt[i] : 0;
        sdata[threadIdx.x] = v;
        __syncthreads();
        for (int off = 1; off < 1024; off <<= 1) {
            int t = (threadIdx.x >= (unsigned)off) ? sdata[threadIdx.x - off] : 0;
            __syncthreads();
            sdata[threadIdx.x] += t;
            __syncthreads();
        }
        int inc = sdata[threadIdx.x] + carry_s;
        if (i < N) rowptr[i + 1] = inc;
        __syncthreads();
        if (threadIdx.x == 1023) carry_s = inc;
        __syncthreads();
    }
}

__global__ void copy_kernel(const int* __restrict__ a, int* __restrict__ b, int N) {
    int i = blockIdx.x * 256 + threadIdx.x;
    if (i < N) b[i] = a[i];
}

// scatter srcs sorted by dst: srcs[pos] = src[e]
__global__ void scatter_kernel(const int* __restrict__ src, const int* __restrict__ dst,
                               int* __restrict__ cursor, int* __restrict__ srcs, int E) {
    int e = blockIdx.x * 256 + threadIdx.x;
    if (e < E) {
        int pos = atomicAdd(&cursor[dst[e]], 1);
        srcs[pos] = src[e];
    }
}

// ---------------- GEMM: C[M,256] = A[M,256] @ B[256,256], fp32 ----------------
#define TM 128
#define TN 128
#define TK 16
__global__ __launch_bounds__(256) void gemm_kernel(const float* __restrict__ A,
                                                   const float* __restrict__ B,
                                                   float* __restrict__ C, int M) {
    __shared__ float As[TK][TM + 4];
    __shared__ float Bs[TK][TN + 4];
    const int t = threadIdx.x;
    const int row0 = blockIdx.x * TM;
    const int col0 = blockIdx.y * TN;
    const int rm0 = (t >> 4) * 4;   // 0..60
    const int cn0 = (t & 15) * 4;   // 0..60

    float acc[8][8];
#pragma unroll
    for (int i = 0; i < 8; ++i)
#pragma unroll
        for (int j = 0; j < 8; ++j) acc[i][j] = 0.f;

    for (int kk = 0; kk < 256; kk += TK) {
        // A tile 128x16 -> As[k][m]
#pragma unroll
        for (int r = 0; r < 2; ++r) {
            int row = (t >> 2) + r * 64;      // 0..127
            int c4 = (t & 3) * 4;             // 0,4,8,12
            float4 v = make_float4(0.f, 0.f, 0.f, 0.f);
            int grow = row0 + row;
            if (grow < M) v = *reinterpret_cast<const float4*>(A + (size_t)grow * 256 + kk + c4);
            As[c4 + 0][row] = v.x;
            As[c4 + 1][row] = v.y;
            As[c4 + 2][row] = v.z;
            As[c4 + 3][row] = v.w;
        }
        // B tile 16x128 -> Bs[k][n]
#pragma unroll
        for (int r = 0; r < 2; ++r) {
            int k = (t >> 5) + r * 8;         // 0..15
            int c4 = (t & 31) * 4;            // 0..124
            float4 v = *reinterpret_cast<const float4*>(B + (size_t)(kk + k) * 256 + col0 + c4);
            *reinterpret_cast<float4*>(&Bs[k][c4]) = v;
        }
        __syncthreads();
#pragma unroll
        for (int k = 0; k < TK; ++k) {
            float4 a0 = *reinterpret_cast<const float4*>(&As[k][rm0]);
            float4 a1 = *reinterpret_cast<const float4*>(&As[k][rm0 + 64]);
            float4 b0 = *reinterpret_cast<const float4*>(&Bs[k][cn0]);
            float4 b1 = *reinterpret_cast<const float4*>(&Bs[k][cn0 + 64]);
            float av[8] = {a0.x, a0.y, a0.z, a0.w, a1.x, a1.y, a1.z, a1.w};
            float bv[8] = {b0.x, b0.y, b0.z, b0.w, b1.x, b1.y, b1.z, b1.w};
#pragma unroll
            for (int i = 0; i < 8; ++i)
#pragma unroll
                for (int j = 0; j < 8; ++j) acc[i][j] = fmaf(av[i], bv[j], acc[i][j]);
        }
        __syncthreads();
    }
#pragma unroll
    for (int i = 0; i < 8; ++i) {
        int lrow = (i < 4) ? (rm0 + i) : (rm0 + 64 + i - 4);
        int grow = row0 + lrow;
        if (grow >= M) continue;
        float4 v0 = make_float4(acc[i][0], acc[i][1], acc[i][2], acc[i][3]);
        float4 v1 = make_float4(acc[i][4], acc[i][5], acc[i][6], acc[i][7]);
        *reinterpret_cast<float4*>(C + (size_t)grow * 256 + col0 + cn0) = v0;
        *reinterpret_cast<float4*>(C + (size_t)grow * 256 + col0 + cn0 + 64) = v1;
    }
}

// ---------------- el/er: per-node head dots ----------------
__global__ void eler_kernel(const float* __restrict__ feat, const float* __restrict__ al,
                            const float* __restrict__ ar, float* __restrict__ el,
                            float* __restrict__ er, int N) {
    int node = blockIdx.x * 4 + (threadIdx.x >> 6);
    if (node >= N) return;
    int lane = threadIdx.x & 63;
    float4 f = *reinterpret_cast<const float4*>(feat + (size_t)node * FDIM + lane * 4);
    float4 a = *reinterpret_cast<const float4*>(al + lane * 4);
    float4 b = *reinterpret_cast<const float4*>(ar + lane * 4);
    float pl = f.x * a.x + f.y * a.y + f.z * a.z + f.w * a.w;
    float pr = f.x * b.x + f.y * b.y + f.z * b.z + f.w * b.w;
#pragma unroll
    for (int m = 1; m < 16; m <<= 1) {
        pl += __shfl_xor(pl, m, 64);
        pr += __shfl_xor(pr, m, 64);
    }
    if ((lane & 15) == 0) {
        int h = lane >> 4;
        el[node * NHEAD + h] = pl;
        er[node * NHEAD + h] = pr;
    }
}

// ---------------- fused softmax + aggregation: one wave per dst node ----------------
// Online (flash-style) softmax over incoming edges; no atomics, no edge buffers.
__global__ __launch_bounds__(256) void agg_fused_kernel(
        const float* __restrict__ feat, const float* __restrict__ el,
        const float* __restrict__ er, const int* __restrict__ rowptr,
        const int* __restrict__ srcs, const float* __restrict__ resid,
        float* __restrict__ out, int N) {
    int node = blockIdx.x * 4 + (threadIdx.x >> 6);
    if (node >= N) return;
    int lane = threadIdx.x & 63;
    int head = lane >> 4;
    float erh = er[(size_t)node * NHEAD + head];

    float m = -1e30f;       // running max (same across the 16 lanes of a head)
    float l = 0.f;          // running denom
    float4 acc = make_float4(0.f, 0.f, 0.f, 0.f);

    int beg = rowptr[node], end = rowptr[node + 1];
    for (int p = beg; p < end; ++p) {
        int s = srcs[p];
        float x = el[(size_t)s * NHEAD + head] + erh;   // 4B load, cache-line broadcast
        x = x > 0.f ? x : 0.2f * x;                     // leaky relu
        float mnew = fmaxf(m, x);
        float scale = __expf(m - mnew);                 // ==1 when max unchanged
        float pe = __expf(x - mnew);
        m = mnew;
        l = l * scale + pe;
        float4 f = *reinterpret_cast<const float4*>(feat + (size_t)s * FDIM + lane * 4);
        acc.x = fmaf(pe, f.x, acc.x * scale);
        acc.y = fmaf(pe, f.y, acc.y * scale);
        acc.z = fmaf(pe, f.z, acc.z * scale);
        acc.w = fmaf(pe, f.w, acc.w * scale);
    }
    float dinv = l > 0.f ? 1.0f / l : 0.f;
    acc.x *= dinv; acc.y *= dinv; acc.z *= dinv; acc.w *= dinv;
    if (resid) {
        float4 r = *reinterpret_cast<const float4*>(resid + (size_t)node * FDIM + lane * 4);
        acc.x += r.x; acc.y += r.y; acc.z += r.z; acc.w += r.w;
    }
    acc.x = acc.x > 0.f ? acc.x : expm1f(acc.x);
    acc.y = acc.y > 0.f ? acc.y : expm1f(acc.y);
    acc.z = acc.z > 0.f ? acc.z : expm1f(acc.z);
    acc.w = acc.w > 0.f ? acc.w : expm1f(acc.w);
    *reinterpret_cast<float4*>(out + (size_t)node * FDIM + lane * 4) = acc;
}

// ---------------- launch ----------------
extern "C" void kernel_launch(void* const* d_in, const int* in_sizes, int n_in,
                              void* d_out, int out_size, void* d_ws, size_t ws_size,
                              hipStream_t stream) {
    const float* features = (const float*)d_in[0];
    const int*   src      = (const int*)d_in[1];
    const int*   dst      = (const int*)d_in[2];
    const float* W1       = (const float*)d_in[3];
    const float* al1      = (const float*)d_in[4];
    const float* ar1      = (const float*)d_in[5];
    const float* W2       = (const float*)d_in[6];
    const float* al2      = (const float*)d_in[7];
    const float* ar2      = (const float*)d_in[8];
    float* out = (float*)d_out;

    const int N = N_NODES, E = N_EDGES;

    char* ws = (char*)d_ws;
    size_t off = 0;
    auto alloc = [&](size_t bytes) -> void* {
        void* p = ws + off;
        off = (off + bytes + 255) & ~(size_t)255;
        return p;
    };
    float* feat   = (float*)alloc((size_t)N * FDIM * 4);
    float* h2     = (float*)alloc((size_t)N * FDIM * 4);
    float* el     = (float*)alloc((size_t)N * NHEAD * 4);
    float* er     = (float*)alloc((size_t)N * NHEAD * 4);
    int*   rowptr = (int*)alloc((size_t)(N + 1) * 4);
    int*   cursor = (int*)alloc((size_t)N * 4);
    int*   srcs   = (int*)alloc((size_t)E * 4);

    const int egrid = (E + 255) / 256;
    const int ngrid4 = (N + 3) / 4;

    // ---- CSR build (by dst), src values pre-gathered ----
    hipMemsetAsync(cursor, 0, (size_t)N * 4, stream);
    degree_kernel<<<egrid, 256, 0, stream>>>(dst, cursor, E);
    scan_kernel<<<1, 1024, 0, stream>>>(cursor, rowptr, N);
    copy_kernel<<<(N + 255) / 256, 256, 0, stream>>>(rowptr, cursor, N);
    scatter_kernel<<<egrid, 256, 0, stream>>>(src, dst, cursor, srcs, E);

    dim3 ggrid((N + TM - 1) / TM, FDIM / TN);

    // ---- layer 1 ----
    gemm_kernel<<<ggrid, 256, 0, stream>>>(features, W1, feat, N);
    eler_kernel<<<ngrid4, 256, 0, stream>>>(feat, al1, ar1, el, er, N);
    agg_fused_kernel<<<ngrid4, 256, 0, stream>>>(feat, el, er, rowptr, srcs, nullptr, h2, N);

    // ---- layer 2 (residual) ----
    gemm_kernel<<<ggrid, 256, 0, stream>>>(h2, W2, feat, N);
    eler_kernel<<<ngrid4, 256, 0, stream>>>(feat, al2, ar2, el, er, N);
    agg_fused_kernel<<<ngrid4, 256, 0, stream>>>(feat, el, er, rowptr, srcs, h2, out, N);
}

// Round 3
// 473.942 us; speedup vs baseline: 2.7344x; 1.3794x over previous
//
#include <hip/hip_runtime.h>
#include <hip/hip_bf16.h>

#define N_NODES 50000
#define N_EDGES 800000
#define NHEAD 4
#define DHEAD 64
#define FDIM 256   // NHEAD*DHEAD == in_feats == out_feats

typedef __attribute__((ext_vector_type(8))) short bfrag8;   // 8 bf16 (4 VGPRs)
typedef __attribute__((ext_vector_type(4))) float f32x4;    // 4 fp32 acc

// ---------------- bf16 helpers (bit ops; bf16->f32 is exact shift) ----------------
__device__ __forceinline__ unsigned f2bf_rne(float x) {
    unsigned u = __float_as_uint(x);
    return (u + 0x7fffu + ((u >> 16) & 1u)) >> 16;
}
__device__ __forceinline__ float bf2f(unsigned u) {
    return __uint_as_float(u << 16);
}

// ---------------- CSR build ----------------
__global__ void degree_kernel(const int* __restrict__ dst, int* __restrict__ cnt, int E) {
    int e = blockIdx.x * 256 + threadIdx.x;
    if (e < E) atomicAdd(&cnt[dst[e]], 1);
}

__global__ void scan_kernel(const int* __restrict__ cnt, int* __restrict__ rowptr, int N) {
    __shared__ int sdata[1024];
    __shared__ int carry_s;
    if (threadIdx.x == 0) { carry_s = 0; rowptr[0] = 0; }
    __syncthreads();
    for (int base = 0; base < N; base += 1024) {
        int i = base + (int)threadIdx.x;
        int v = (i < N) ? cnt[i] : 0;
        sdata[threadIdx.x] = v;
        __syncthreads();
        for (int off = 1; off < 1024; off <<= 1) {
            int t = (threadIdx.x >= (unsigned)off) ? sdata[threadIdx.x - off] : 0;
            __syncthreads();
            sdata[threadIdx.x] += t;
            __syncthreads();
        }
        int inc = sdata[threadIdx.x] + carry_s;
        if (i < N) rowptr[i + 1] = inc;
        __syncthreads();
        if (threadIdx.x == 1023) carry_s = inc;
        __syncthreads();
    }
}

__global__ void copy_kernel(const int* __restrict__ a, int* __restrict__ b, int N) {
    int i = blockIdx.x * 256 + threadIdx.x;
    if (i < N) b[i] = a[i];
}

__global__ void scatter_kernel(const int* __restrict__ src, const int* __restrict__ dst,
                               int* __restrict__ cursor, int* __restrict__ srcs, int E) {
    int e = blockIdx.x * 256 + threadIdx.x;
    if (e < E) {
        int pos = atomicAdd(&cursor[dst[e]], 1);
        srcs[pos] = src[e];
    }
}

// ---------------- W split+transpose: B[256][256] fp32 -> Bth/Btl[n][k] bf16 ----------------
__global__ __launch_bounds__(256) void bconv_kernel(const float* __restrict__ B,
                                                    ushort* __restrict__ Bth,
                                                    ushort* __restrict__ Btl) {
    __shared__ ushort th[16][264], tl[16][264];
    int k0 = blockIdx.x * 16;       // 16 k-rows per block
    int n = threadIdx.x;            // 0..255
#pragma unroll
    for (int k = 0; k < 16; ++k) {
        float v = B[(size_t)(k0 + k) * 256 + n];
        unsigned hb = f2bf_rne(v);
        th[k][n] = (ushort)hb;
        tl[k][n] = (ushort)(__float_as_uint(v - bf2f(hb)) >> 16);  // trunc lo: fine
    }
    __syncthreads();
    ushort oh[16], ol[16];
#pragma unroll
    for (int k = 0; k < 16; ++k) { oh[k] = th[k][n]; ol[k] = tl[k][n]; }
#pragma unroll
    for (int q = 0; q < 4; ++q) {
        *reinterpret_cast<ushort4*>(Bth + (size_t)n * 256 + k0 + q * 4) =
            make_ushort4(oh[q*4+0], oh[q*4+1], oh[q*4+2], oh[q*4+3]);
        *reinterpret_cast<ushort4*>(Btl + (size_t)n * 256 + k0 + q * 4) =
            make_ushort4(ol[q*4+0], ol[q*4+1], ol[q*4+2], ol[q*4+3]);
    }
}

// ---------------- GEMM: Cb[M,256](bf16) = A[M,256](fp32) @ B, split-bf16 MFMA ----------------
// A split on the fly into hi/lo bf16; C = Ah*Bh + Ah*Bl + Al*Bh (Al*Bl dropped, ~1e-6 rel).
__global__ __launch_bounds__(256) void gemm_mfma_kernel(const float* __restrict__ A,
                                                        const ushort* __restrict__ Bth,
                                                        const ushort* __restrict__ Btl,
                                                        ushort* __restrict__ Cb, int M) {
    __shared__ ushort Ah[128][40], Al[128][40];   // [m][k], padded: row stride 80B (16B-aligned)
    __shared__ ushort Bh[128][40], Bl[128][40];   // [n][k] (transposed tile)
    const int t = threadIdx.x;
    const int lane = t & 63, wave = t >> 6;
    const int wr = wave >> 1, wc = wave & 1;      // wave covers 64x64 at (wr*64, wc*64)
    const int row0 = blockIdx.x * 128;
    const int col0 = blockIdx.y * 128;

    f32x4 acc[4][4];
#pragma unroll
    for (int i = 0; i < 4; ++i)
#pragma unroll
        for (int j = 0; j < 4; ++j) { acc[i][j].x = 0.f; acc[i][j].y = 0.f; acc[i][j].z = 0.f; acc[i][j].w = 0.f; }

    const int srow = t >> 1;            // 0..127
    const int skoff = (t & 1) * 16;     // 0 or 16

    for (int kk = 0; kk < 256; kk += 32) {
        // ---- stage A tile 128x32 fp32 -> bf16 hi/lo ----
        {
            int grow = row0 + srow;
            float v[16];
            if (grow < M) {
                const float4* p = reinterpret_cast<const float4*>(A + (size_t)grow * 256 + kk + skoff);
#pragma unroll
                for (int q = 0; q < 4; ++q) {
                    float4 x = p[q];
                    v[q*4+0] = x.x; v[q*4+1] = x.y; v[q*4+2] = x.z; v[q*4+3] = x.w;
                }
            } else {
#pragma unroll
                for (int q = 0; q < 16; ++q) v[q] = 0.f;
            }
            ushort hh[16], ll[16];
#pragma unroll
            for (int q = 0; q < 16; ++q) {
                unsigned hb = f2bf_rne(v[q]);
                hh[q] = (ushort)hb;
                ll[q] = (ushort)(__float_as_uint(v[q] - bf2f(hb)) >> 16);
            }
#pragma unroll
            for (int q = 0; q < 4; ++q) {
                *reinterpret_cast<ushort4*>(&Ah[srow][skoff + q * 4]) =
                    make_ushort4(hh[q*4+0], hh[q*4+1], hh[q*4+2], hh[q*4+3]);
                *reinterpret_cast<ushort4*>(&Al[srow][skoff + q * 4]) =
                    make_ushort4(ll[q*4+0], ll[q*4+1], ll[q*4+2], ll[q*4+3]);
            }
        }
        // ---- stage B tile 128(col)x32(k) from pre-transposed bf16 ----
        {
            const ushort* ph = Bth + (size_t)(col0 + srow) * 256 + kk + skoff;
            const ushort* pl = Btl + (size_t)(col0 + srow) * 256 + kk + skoff;
#pragma unroll
            for (int q = 0; q < 4; ++q) {
                *reinterpret_cast<ushort4*>(&Bh[srow][skoff + q * 4]) =
                    *reinterpret_cast<const ushort4*>(ph + q * 4);
                *reinterpret_cast<ushort4*>(&Bl[srow][skoff + q * 4]) =
                    *reinterpret_cast<const ushort4*>(pl + q * 4);
            }
        }
        __syncthreads();
        // ---- fragments + MFMA ----
        const int kg = (lane >> 4) * 8;   // k offset within tile
        const int rsel = lane & 15;
        bfrag8 afh[4], afl[4], bfh[4], bfl[4];
#pragma unroll
        for (int i = 0; i < 4; ++i) {
            afh[i] = *reinterpret_cast<const bfrag8*>(&Ah[wr * 64 + i * 16 + rsel][kg]);
            afl[i] = *reinterpret_cast<const bfrag8*>(&Al[wr * 64 + i * 16 + rsel][kg]);
        }
#pragma unroll
        for (int j = 0; j < 4; ++j) {
            bfh[j] = *reinterpret_cast<const bfrag8*>(&Bh[wc * 64 + j * 16 + rsel][kg]);
            bfl[j] = *reinterpret_cast<const bfrag8*>(&Bl[wc * 64 + j * 16 + rsel][kg]);
        }
#pragma unroll
        for (int i = 0; i < 4; ++i)
#pragma unroll
            for (int j = 0; j < 4; ++j) {
                acc[i][j] = __builtin_amdgcn_mfma_f32_16x16x32_bf16(afh[i], bfh[j], acc[i][j], 0, 0, 0);
                acc[i][j] = __builtin_amdgcn_mfma_f32_16x16x32_bf16(afh[i], bfl[j], acc[i][j], 0, 0, 0);
                acc[i][j] = __builtin_amdgcn_mfma_f32_16x16x32_bf16(afl[i], bfh[j], acc[i][j], 0, 0, 0);
            }
        __syncthreads();
    }
    // ---- epilogue: C/D layout col=lane&15, row=(lane>>4)*4+r ----
    const int ccol = lane & 15;
    const int crow = (lane >> 4) * 4;
#pragma unroll
    for (int i = 0; i < 4; ++i) {
#pragma unroll
        for (int r = 0; r < 4; ++r) {
            int row = row0 + wr * 64 + i * 16 + crow + r;
            if (row >= M) continue;
#pragma unroll
            for (int j = 0; j < 4; ++j) {
                int col = col0 + wc * 64 + j * 16 + ccol;
                float val = (r == 0) ? acc[i][j].x : (r == 1) ? acc[i][j].y : (r == 2) ? acc[i][j].z : acc[i][j].w;
                Cb[(size_t)row * 256 + col] = (ushort)f2bf_rne(val);
            }
        }
    }
}

// ---------------- el/er: per-node head dots (bf16 feat) ----------------
__global__ void eler_kernel(const ushort* __restrict__ featb, const float* __restrict__ al,
                            const float* __restrict__ ar, float* __restrict__ el,
                            float* __restrict__ er, int N) {
    int node = blockIdx.x * 4 + (threadIdx.x >> 6);
    if (node >= N) return;
    int lane = threadIdx.x & 63;
    ushort4 fu = *reinterpret_cast<const ushort4*>(featb + (size_t)node * FDIM + lane * 4);
    float f0 = bf2f(fu.x), f1 = bf2f(fu.y), f2 = bf2f(fu.z), f3 = bf2f(fu.w);
    float4 a = *reinterpret_cast<const float4*>(al + lane * 4);
    float4 b = *reinterpret_cast<const float4*>(ar + lane * 4);
    float pl = f0 * a.x + f1 * a.y + f2 * a.z + f3 * a.w;
    float pr = f0 * b.x + f1 * b.y + f2 * b.z + f3 * b.w;
#pragma unroll
    for (int m = 1; m < 16; m <<= 1) {
        pl += __shfl_xor(pl, m, 64);
        pr += __shfl_xor(pr, m, 64);
    }
    if ((lane & 15) == 0) {
        int h = lane >> 4;
        el[node * NHEAD + h] = pl;
        er[node * NHEAD + h] = pr;
    }
}

// ---------------- fused softmax + aggregation (bf16 gather, online softmax) ----------------
__global__ __launch_bounds__(256) void agg_fused_kernel(
        const ushort* __restrict__ featb, const float* __restrict__ el,
        const float* __restrict__ er, const int* __restrict__ rowptr,
        const int* __restrict__ srcs, const float* __restrict__ resid,
        float* __restrict__ out, int N) {
    int node = blockIdx.x * 4 + (threadIdx.x >> 6);
    if (node >= N) return;
    int lane = threadIdx.x & 63;
    int head = lane >> 4;
    float erh = er[(size_t)node * NHEAD + head];

    float m = -1e30f;
    float l = 0.f;
    float4 acc = make_float4(0.f, 0.f, 0.f, 0.f);

    int beg = rowptr[node], end = rowptr[node + 1];
    for (int p = beg; p < end; ++p) {
        int s = srcs[p];
        float x = el[(size_t)s * NHEAD + head] + erh;
        x = x > 0.f ? x : 0.2f * x;
        float mnew = fmaxf(m, x);
        float scale = __expf(m - mnew);
        float pe = __expf(x - mnew);
        m = mnew;
        l = l * scale + pe;
        ushort4 fu = *reinterpret_cast<const ushort4*>(featb + (size_t)s * FDIM + lane * 4);
        acc.x = fmaf(pe, bf2f(fu.x), acc.x * scale);
        acc.y = fmaf(pe, bf2f(fu.y), acc.y * scale);
        acc.z = fmaf(pe, bf2f(fu.z), acc.z * scale);
        acc.w = fmaf(pe, bf2f(fu.w), acc.w * scale);
    }
    float dinv = l > 0.f ? 1.0f / l : 0.f;
    acc.x *= dinv; acc.y *= dinv; acc.z *= dinv; acc.w *= dinv;
    if (resid) {
        float4 r = *reinterpret_cast<const float4*>(resid + (size_t)node * FDIM + lane * 4);
        acc.x += r.x; acc.y += r.y; acc.z += r.z; acc.w += r.w;
    }
    acc.x = acc.x > 0.f ? acc.x : expm1f(acc.x);
    acc.y = acc.y > 0.f ? acc.y : expm1f(acc.y);
    acc.z = acc.z > 0.f ? acc.z : expm1f(acc.z);
    acc.w = acc.w > 0.f ? acc.w : expm1f(acc.w);
    *reinterpret_cast<float4*>(out + (size_t)node * FDIM + lane * 4) = acc;
}

// ---------------- launch ----------------
extern "C" void kernel_launch(void* const* d_in, const int* in_sizes, int n_in,
                              void* d_out, int out_size, void* d_ws, size_t ws_size,
                              hipStream_t stream) {
    const float* features = (const float*)d_in[0];
    const int*   src      = (const int*)d_in[1];
    const int*   dst      = (const int*)d_in[2];
    const float* W1       = (const float*)d_in[3];
    const float* al1      = (const float*)d_in[4];
    const float* ar1      = (const float*)d_in[5];
    const float* W2       = (const float*)d_in[6];
    const float* al2      = (const float*)d_in[7];
    const float* ar2      = (const float*)d_in[8];
    float* out = (float*)d_out;

    const int N = N_NODES, E = N_EDGES;

    char* ws = (char*)d_ws;
    size_t off = 0;
    auto alloc = [&](size_t bytes) -> void* {
        void* p = ws + off;
        off = (off + bytes + 255) & ~(size_t)255;
        return p;
    };
    ushort* featb  = (ushort*)alloc((size_t)N * FDIM * 2);
    float*  h2     = (float*)alloc((size_t)N * FDIM * 4);
    float*  el     = (float*)alloc((size_t)N * NHEAD * 4);
    float*  er     = (float*)alloc((size_t)N * NHEAD * 4);
    int*    rowptr = (int*)alloc((size_t)(N + 1) * 4);
    int*    cursor = (int*)alloc((size_t)N * 4);
    int*    srcs   = (int*)alloc((size_t)E * 4);
    ushort* Bth    = (ushort*)alloc((size_t)256 * 256 * 2);
    ushort* Btl    = (ushort*)alloc((size_t)256 * 256 * 2);

    const int egrid = (E + 255) / 256;
    const int ngrid4 = (N + 3) / 4;

    // ---- CSR build (by dst), src values pre-gathered ----
    hipMemsetAsync(cursor, 0, (size_t)N * 4, stream);
    degree_kernel<<<egrid, 256, 0, stream>>>(dst, cursor, E);
    scan_kernel<<<1, 1024, 0, stream>>>(cursor, rowptr, N);
    copy_kernel<<<(N + 255) / 256, 256, 0, stream>>>(rowptr, cursor, N);
    scatter_kernel<<<egrid, 256, 0, stream>>>(src, dst, cursor, srcs, E);

    dim3 ggrid((N + 127) / 128, 2);

    // ---- layer 1 ----
    bconv_kernel<<<16, 256, 0, stream>>>(W1, Bth, Btl);
    gemm_mfma_kernel<<<ggrid, 256, 0, stream>>>(features, Bth, Btl, featb, N);
    eler_kernel<<<ngrid4, 256, 0, stream>>>(featb, al1, ar1, el, er, N);
    agg_fused_kernel<<<ngrid4, 256, 0, stream>>>(featb, el, er, rowptr, srcs, nullptr, h2, N);

    // ---- layer 2 (residual) ----
    bconv_kernel<<<16, 256, 0, stream>>>(W2, Bth, Btl);
    gemm_mfma_kernel<<<ggrid, 256, 0, stream>>>(h2, Bth, Btl, featb, N);
    eler_kernel<<<ngrid4, 256, 0, stream>>>(featb, al2, ar2, el, er, N);
    agg_fused_kernel<<<ngrid4, 256, 0, stream>>>(featb, el, er, rowptr, srcs, h2, out, N);
}

// Round 4
// 390.950 us; speedup vs baseline: 3.3149x; 1.2123x over previous
//
#include <hip/hip_runtime.h>
#include <hip/hip_bf16.h>

#define N_NODES 50000
#define N_EDGES 800000
#define NHEAD 4
#define DHEAD 64
#define FDIM 256   // NHEAD*DHEAD == in_feats == out_feats
#define SCANB 1024
#define NSCAN ((N_NODES + SCANB - 1) / SCANB)   // 49

typedef __attribute__((ext_vector_type(8))) short bfrag8;   // 8 bf16 (4 VGPRs)
typedef __attribute__((ext_vector_type(4))) float f32x4;    // 4 fp32 acc

// ---------------- bf16 helpers ----------------
__device__ __forceinline__ unsigned f2bf_rne(float x) {
    unsigned u = __float_as_uint(x);
    return (u + 0x7fffu + ((u >> 16) & 1u)) >> 16;
}
__device__ __forceinline__ float bf2f(unsigned u) {
    return __uint_as_float(u << 16);
}

// ---------------- CSR build ----------------
__global__ void degree_kernel(const int* __restrict__ dst, int* __restrict__ cnt, int E) {
    int e = blockIdx.x * 256 + threadIdx.x;
    if (e < E) atomicAdd(&cnt[dst[e]], 1);
}

__global__ __launch_bounds__(1024) void scan1_kernel(const int* __restrict__ cnt,
                                                     int* __restrict__ partial,
                                                     int* __restrict__ bsum, int N) {
    __shared__ int sdata[SCANB];
    int i = blockIdx.x * SCANB + (int)threadIdx.x;
    int v = (i < N) ? cnt[i] : 0;
    sdata[threadIdx.x] = v;
    __syncthreads();
    for (int off = 1; off < SCANB; off <<= 1) {
        int t = (threadIdx.x >= (unsigned)off) ? sdata[threadIdx.x - off] : 0;
        __syncthreads();
        sdata[threadIdx.x] += t;
        __syncthreads();
    }
    if (i < N) partial[i] = sdata[threadIdx.x];
    if (threadIdx.x == SCANB - 1) bsum[blockIdx.x] = sdata[SCANB - 1];
}

__global__ void scan2_kernel(const int* __restrict__ bsum, int* __restrict__ boff, int nb) {
    int lane = threadIdx.x;   // 64 threads
    int v = (lane < nb) ? bsum[lane] : 0;
#pragma unroll
    for (int off = 1; off < 64; off <<= 1) {
        int o = __shfl_up(v, off, 64);
        if (lane >= off) v += o;
    }
    int excl = __shfl_up(v, 1, 64);
    if (lane == 0) excl = 0;
    if (lane < nb) boff[lane] = excl;
}

__global__ __launch_bounds__(1024) void scan3_kernel(const int* __restrict__ partial,
                                                     const int* __restrict__ boff,
                                                     int* __restrict__ rowptr,
                                                     int* __restrict__ cursor, int N) {
    int i = blockIdx.x * SCANB + (int)threadIdx.x;
    if (i < N) {
        int inc = partial[i] + boff[blockIdx.x];
        rowptr[i + 1] = inc;
        if (i + 1 < N) cursor[i + 1] = inc;
    }
    if (i == 0) { rowptr[0] = 0; cursor[0] = 0; }
}

__global__ void scatter_kernel(const int* __restrict__ src, const int* __restrict__ dst,
                               int* __restrict__ cursor, int* __restrict__ srcs, int E) {
    int e = blockIdx.x * 256 + threadIdx.x;
    if (e < E) {
        int pos = atomicAdd(&cursor[dst[e]], 1);
        srcs[pos] = src[e];
    }
}

// ---------------- A split: fp32 -> hi/lo bf16 ----------------
__global__ void asplit_kernel(const float* __restrict__ A, ushort* __restrict__ Ah,
                              ushort* __restrict__ Al, int n4) {
    int i = blockIdx.x * 256 + threadIdx.x;
    if (i >= n4) return;
    float4 v = reinterpret_cast<const float4*>(A)[i];
    unsigned h0 = f2bf_rne(v.x), h1 = f2bf_rne(v.y), h2 = f2bf_rne(v.z), h3 = f2bf_rne(v.w);
    reinterpret_cast<ushort4*>(Ah)[i] = make_ushort4((ushort)h0, (ushort)h1, (ushort)h2, (ushort)h3);
    reinterpret_cast<ushort4*>(Al)[i] = make_ushort4(
        (ushort)(__float_as_uint(v.x - bf2f(h0)) >> 16),
        (ushort)(__float_as_uint(v.y - bf2f(h1)) >> 16),
        (ushort)(__float_as_uint(v.z - bf2f(h2)) >> 16),
        (ushort)(__float_as_uint(v.w - bf2f(h3)) >> 16));
}

// ---------------- W split+transpose: B[256][256] fp32 -> Bth/Btl[n][k] bf16 ----------------
__global__ __launch_bounds__(256) void bconv_kernel(const float* __restrict__ B,
                                                    ushort* __restrict__ Bth,
                                                    ushort* __restrict__ Btl) {
    __shared__ ushort th[16][264], tl[16][264];
    int k0 = blockIdx.x * 16;
    int n = threadIdx.x;
#pragma unroll
    for (int k = 0; k < 16; ++k) {
        float v = B[(size_t)(k0 + k) * 256 + n];
        unsigned hb = f2bf_rne(v);
        th[k][n] = (ushort)hb;
        tl[k][n] = (ushort)(__float_as_uint(v - bf2f(hb)) >> 16);
    }
    __syncthreads();
    ushort oh[16], ol[16];
#pragma unroll
    for (int k = 0; k < 16; ++k) { oh[k] = th[k][n]; ol[k] = tl[k][n]; }
#pragma unroll
    for (int q = 0; q < 4; ++q) {
        *reinterpret_cast<ushort4*>(Bth + (size_t)n * 256 + k0 + q * 4) =
            make_ushort4(oh[q*4+0], oh[q*4+1], oh[q*4+2], oh[q*4+3]);
        *reinterpret_cast<ushort4*>(Btl + (size_t)n * 256 + k0 + q * 4) =
            make_ushort4(ol[q*4+0], ol[q*4+1], ol[q*4+2], ol[q*4+3]);
    }
}

// ---------------- GEMM: Cb[M,256](bf16) = (Ah+Al) @ (Bh+Bl), split-bf16 MFMA ----------------
__global__ __launch_bounds__(256) void gemm_mfma_kernel(const ushort* __restrict__ Ahg,
                                                        const ushort* __restrict__ Alg,
                                                        const ushort* __restrict__ Bth,
                                                        const ushort* __restrict__ Btl,
                                                        ushort* __restrict__ Cb, int M) {
    __shared__ ushort Ah[128][40], Al[128][40];   // [m][k], padded rows (80B stride)
    __shared__ ushort Bh[128][40], Bl[128][40];   // [n][k]
    const int t = threadIdx.x;
    const int lane = t & 63, wave = t >> 6;
    const int wr = wave >> 1, wc = wave & 1;
    const int row0 = blockIdx.x * 128;
    const int col0 = blockIdx.y * 128;

    f32x4 acc[4][4];
#pragma unroll
    for (int i = 0; i < 4; ++i)
#pragma unroll
        for (int j = 0; j < 4; ++j) { acc[i][j].x = 0.f; acc[i][j].y = 0.f; acc[i][j].z = 0.f; acc[i][j].w = 0.f; }

    const int srow = t >> 1;            // 0..127
    const int skoff = (t & 1) * 16;     // 0 or 16
    int arow = row0 + srow; if (arow >= M) arow = M - 1;   // clamp; stores are guarded
    const size_t abase = (size_t)arow * 256 + skoff;
    const size_t bbase = (size_t)(col0 + srow) * 256 + skoff;

    for (int kk = 0; kk < 256; kk += 32) {
        const uint4* pah = reinterpret_cast<const uint4*>(Ahg + abase + kk);
        const uint4* pal = reinterpret_cast<const uint4*>(Alg + abase + kk);
        const uint4* pbh = reinterpret_cast<const uint4*>(Bth + bbase + kk);
        const uint4* pbl = reinterpret_cast<const uint4*>(Btl + bbase + kk);
        *reinterpret_cast<uint4*>(&Ah[srow][skoff])     = pah[0];
        *reinterpret_cast<uint4*>(&Ah[srow][skoff + 8]) = pah[1];
        *reinterpret_cast<uint4*>(&Al[srow][skoff])     = pal[0];
        *reinterpret_cast<uint4*>(&Al[srow][skoff + 8]) = pal[1];
        *reinterpret_cast<uint4*>(&Bh[srow][skoff])     = pbh[0];
        *reinterpret_cast<uint4*>(&Bh[srow][skoff + 8]) = pbh[1];
        *reinterpret_cast<uint4*>(&Bl[srow][skoff])     = pbl[0];
        *reinterpret_cast<uint4*>(&Bl[srow][skoff + 8]) = pbl[1];
        __syncthreads();

        const int kg = (lane >> 4) * 8;
        const int rsel = lane & 15;
        bfrag8 afh[4], afl[4], bfh[4], bfl[4];
#pragma unroll
        for (int i = 0; i < 4; ++i) {
            afh[i] = *reinterpret_cast<const bfrag8*>(&Ah[wr * 64 + i * 16 + rsel][kg]);
            afl[i] = *reinterpret_cast<const bfrag8*>(&Al[wr * 64 + i * 16 + rsel][kg]);
        }
#pragma unroll
        for (int j = 0; j < 4; ++j) {
            bfh[j] = *reinterpret_cast<const bfrag8*>(&Bh[wc * 64 + j * 16 + rsel][kg]);
            bfl[j] = *reinterpret_cast<const bfrag8*>(&Bl[wc * 64 + j * 16 + rsel][kg]);
        }
#pragma unroll
        for (int i = 0; i < 4; ++i)
#pragma unroll
            for (int j = 0; j < 4; ++j) {
                acc[i][j] = __builtin_amdgcn_mfma_f32_16x16x32_bf16(afh[i], bfh[j], acc[i][j], 0, 0, 0);
                acc[i][j] = __builtin_amdgcn_mfma_f32_16x16x32_bf16(afh[i], bfl[j], acc[i][j], 0, 0, 0);
                acc[i][j] = __builtin_amdgcn_mfma_f32_16x16x32_bf16(afl[i], bfh[j], acc[i][j], 0, 0, 0);
            }
        __syncthreads();
    }
    const int ccol = lane & 15;
    const int crow = (lane >> 4) * 4;
#pragma unroll
    for (int i = 0; i < 4; ++i) {
#pragma unroll
        for (int r = 0; r < 4; ++r) {
            int row = row0 + wr * 64 + i * 16 + crow + r;
            if (row >= M) continue;
#pragma unroll
            for (int j = 0; j < 4; ++j) {
                int col = col0 + wc * 64 + j * 16 + ccol;
                float val = (r == 0) ? acc[i][j].x : (r == 1) ? acc[i][j].y : (r == 2) ? acc[i][j].z : acc[i][j].w;
                Cb[(size_t)row * 256 + col] = (ushort)f2bf_rne(val);
            }
        }
    }
}

// ---------------- el/er: per-node head dots (bf16 feat) ----------------
__global__ void eler_kernel(const ushort* __restrict__ featb, const float* __restrict__ al,
                            const float* __restrict__ ar, float* __restrict__ el,
                            float* __restrict__ er, int N) {
    int node = blockIdx.x * 4 + (threadIdx.x >> 6);
    if (node >= N) return;
    int lane = threadIdx.x & 63;
    ushort4 fu = *reinterpret_cast<const ushort4*>(featb + (size_t)node * FDIM + lane * 4);
    float f0 = bf2f(fu.x), f1 = bf2f(fu.y), f2 = bf2f(fu.z), f3 = bf2f(fu.w);
    float4 a = *reinterpret_cast<const float4*>(al + lane * 4);
    float4 b = *reinterpret_cast<const float4*>(ar + lane * 4);
    float pl = f0 * a.x + f1 * a.y + f2 * a.z + f3 * a.w;
    float pr = f0 * b.x + f1 * b.y + f2 * b.z + f3 * b.w;
#pragma unroll
    for (int m = 1; m < 16; m <<= 1) {
        pl += __shfl_xor(pl, m, 64);
        pr += __shfl_xor(pr, m, 64);
    }
    if ((lane & 15) == 0) {
        int h = lane >> 4;
        el[node * NHEAD + h] = pl;
        er[node * NHEAD + h] = pr;
    }
}

// ---------------- fused softmax + aggregation: two-phase, one wave per node ----------------
// Phase A: 16-lane-parallel softmax stats per head. Phase B: plain weighted gather.
__global__ __launch_bounds__(256) void agg_fused_kernel(
        const ushort* __restrict__ featb, const float* __restrict__ el,
        const float* __restrict__ er, const int* __restrict__ rowptr,
        const int* __restrict__ srcs,
        const ushort* __restrict__ resid_h, const ushort* __restrict__ resid_l,
        float* __restrict__ outf, ushort* __restrict__ outh, ushort* __restrict__ outl,
        int N) {
    int node = blockIdx.x * 4 + (threadIdx.x >> 6);
    if (node >= N) return;
    int lane = threadIdx.x & 63;
    int head = lane >> 4;
    int l16 = lane & 15;
    float erh = er[(size_t)node * NHEAD + head];
    int beg = rowptr[node], end = rowptr[node + 1];

    // ---- phase A: max & denom, lane-parallel (each lane every 16th edge) ----
    float m = -1e30f, lp = 0.f;
    for (int base = beg; base < end; base += 16) {
        int p = base + l16;
        float x = -1e30f;
        if (p < end) {
            int s = srcs[p];
            float t = el[(size_t)s * NHEAD + head] + erh;
            x = t > 0.f ? t : 0.2f * t;
        }
        float cm = x;
        cm = fmaxf(cm, __shfl_xor(cm, 1, 64));
        cm = fmaxf(cm, __shfl_xor(cm, 2, 64));
        cm = fmaxf(cm, __shfl_xor(cm, 4, 64));
        cm = fmaxf(cm, __shfl_xor(cm, 8, 64));
        float mnew = fmaxf(m, cm);
        lp = lp * __expf(m - mnew) + ((p < end) ? __expf(x - mnew) : 0.f);
        m = mnew;
    }
    lp += __shfl_xor(lp, 1, 64);
    lp += __shfl_xor(lp, 2, 64);
    lp += __shfl_xor(lp, 4, 64);
    lp += __shfl_xor(lp, 8, 64);
    float dinv = lp > 0.f ? 1.0f / lp : 0.f;

    // ---- phase B: weighted gather, 2 independent accumulators ----
    float4 a0 = make_float4(0.f, 0.f, 0.f, 0.f);
    float4 a1 = make_float4(0.f, 0.f, 0.f, 0.f);
    int p = beg;
    for (; p + 1 < end; p += 2) {
        int s0 = srcs[p], s1 = srcs[p + 1];
        float t0 = el[(size_t)s0 * NHEAD + head] + erh;
        float t1 = el[(size_t)s1 * NHEAD + head] + erh;
        t0 = t0 > 0.f ? t0 : 0.2f * t0;
        t1 = t1 > 0.f ? t1 : 0.2f * t1;
        float w0 = __expf(t0 - m) * dinv;
        float w1 = __expf(t1 - m) * dinv;
        ushort4 f0 = *reinterpret_cast<const ushort4*>(featb + (size_t)s0 * FDIM + lane * 4);
        ushort4 f1 = *reinterpret_cast<const ushort4*>(featb + (size_t)s1 * FDIM + lane * 4);
        a0.x = fmaf(w0, bf2f(f0.x), a0.x); a1.x = fmaf(w1, bf2f(f1.x), a1.x);
        a0.y = fmaf(w0, bf2f(f0.y), a0.y); a1.y = fmaf(w1, bf2f(f1.y), a1.y);
        a0.z = fmaf(w0, bf2f(f0.z), a0.z); a1.z = fmaf(w1, bf2f(f1.z), a1.z);
        a0.w = fmaf(w0, bf2f(f0.w), a0.w); a1.w = fmaf(w1, bf2f(f1.w), a1.w);
    }
    if (p < end) {
        int s0 = srcs[p];
        float t0 = el[(size_t)s0 * NHEAD + head] + erh;
        t0 = t0 > 0.f ? t0 : 0.2f * t0;
        float w0 = __expf(t0 - m) * dinv;
        ushort4 f0 = *reinterpret_cast<const ushort4*>(featb + (size_t)s0 * FDIM + lane * 4);
        a0.x = fmaf(w0, bf2f(f0.x), a0.x);
        a0.y = fmaf(w0, bf2f(f0.y), a0.y);
        a0.z = fmaf(w0, bf2f(f0.z), a0.z);
        a0.w = fmaf(w0, bf2f(f0.w), a0.w);
    }
    float4 acc = make_float4(a0.x + a1.x, a0.y + a1.y, a0.z + a1.z, a0.w + a1.w);

    if (resid_h) {
        ushort4 rh = *reinterpret_cast<const ushort4*>(resid_h + (size_t)node * FDIM + lane * 4);
        ushort4 rl = *reinterpret_cast<const ushort4*>(resid_l + (size_t)node * FDIM + lane * 4);
        acc.x += bf2f(rh.x) + bf2f(rl.x);
        acc.y += bf2f(rh.y) + bf2f(rl.y);
        acc.z += bf2f(rh.z) + bf2f(rl.z);
        acc.w += bf2f(rh.w) + bf2f(rl.w);
    }
    acc.x = acc.x > 0.f ? acc.x : expm1f(acc.x);
    acc.y = acc.y > 0.f ? acc.y : expm1f(acc.y);
    acc.z = acc.z > 0.f ? acc.z : expm1f(acc.z);
    acc.w = acc.w > 0.f ? acc.w : expm1f(acc.w);

    if (outf) {
        *reinterpret_cast<float4*>(outf + (size_t)node * FDIM + lane * 4) = acc;
    } else {
        unsigned h0 = f2bf_rne(acc.x), h1 = f2bf_rne(acc.y), h2 = f2bf_rne(acc.z), h3 = f2bf_rne(acc.w);
        *reinterpret_cast<ushort4*>(outh + (size_t)node * FDIM + lane * 4) =
            make_ushort4((ushort)h0, (ushort)h1, (ushort)h2, (ushort)h3);
        *reinterpret_cast<ushort4*>(outl + (size_t)node * FDIM + lane * 4) = make_ushort4(
            (ushort)(__float_as_uint(acc.x - bf2f(h0)) >> 16),
            (ushort)(__float_as_uint(acc.y - bf2f(h1)) >> 16),
            (ushort)(__float_as_uint(acc.z - bf2f(h2)) >> 16),
            (ushort)(__float_as_uint(acc.w - bf2f(h3)) >> 16));
    }
}

// ---------------- launch ----------------
extern "C" void kernel_launch(void* const* d_in, const int* in_sizes, int n_in,
                              void* d_out, int out_size, void* d_ws, size_t ws_size,
                              hipStream_t stream) {
    const float* features = (const float*)d_in[0];
    const int*   src      = (const int*)d_in[1];
    const int*   dst      = (const int*)d_in[2];
    const float* W1       = (const float*)d_in[3];
    const float* al1      = (const float*)d_in[4];
    const float* ar1      = (const float*)d_in[5];
    const float* W2       = (const float*)d_in[6];
    const float* al2      = (const float*)d_in[7];
    const float* ar2      = (const float*)d_in[8];
    float* out = (float*)d_out;

    const int N = N_NODES, E = N_EDGES;

    char* ws = (char*)d_ws;
    size_t off = 0;
    auto alloc = [&](size_t bytes) -> void* {
        void* p = ws + off;
        off = (off + bytes + 255) & ~(size_t)255;
        return p;
    };
    ushort* featb  = (ushort*)alloc((size_t)N * FDIM * 2);
    ushort* Afh    = (ushort*)alloc((size_t)N * FDIM * 2);   // layer A hi (reused: agg1 out)
    ushort* Afl    = (ushort*)alloc((size_t)N * FDIM * 2);   // layer A lo
    float*  el     = (float*)alloc((size_t)N * NHEAD * 4);
    float*  er     = (float*)alloc((size_t)N * NHEAD * 4);
    int*    rowptr = (int*)alloc((size_t)(N + 1) * 4);
    int*    cnt    = (int*)alloc((size_t)N * 4);
    int*    cursor = (int*)alloc((size_t)N * 4);
    int*    partial= (int*)alloc((size_t)N * 4);
    int*    bsum   = (int*)alloc((size_t)NSCAN * 4);
    int*    boff   = (int*)alloc((size_t)NSCAN * 4);
    int*    srcs   = (int*)alloc((size_t)E * 4);
    ushort* Bth    = (ushort*)alloc((size_t)256 * 256 * 2);
    ushort* Btl    = (ushort*)alloc((size_t)256 * 256 * 2);

    const int egrid = (E + 255) / 256;
    const int ngrid4 = (N + 3) / 4;

    // ---- CSR build (by dst) ----
    hipMemsetAsync(cnt, 0, (size_t)N * 4, stream);
    degree_kernel<<<egrid, 256, 0, stream>>>(dst, cnt, E);
    scan1_kernel<<<NSCAN, SCANB, 0, stream>>>(cnt, partial, bsum, N);
    scan2_kernel<<<1, 64, 0, stream>>>(bsum, boff, NSCAN);
    scan3_kernel<<<NSCAN, SCANB, 0, stream>>>(partial, boff, rowptr, cursor, N);
    scatter_kernel<<<egrid, 256, 0, stream>>>(src, dst, cursor, srcs, E);

    // ---- input split ----
    asplit_kernel<<<(N * FDIM / 4 + 255) / 256, 256, 0, stream>>>(features, Afh, Afl, N * FDIM / 4);

    dim3 ggrid((N + 127) / 128, 2);

    // ---- layer 1 ----
    bconv_kernel<<<16, 256, 0, stream>>>(W1, Bth, Btl);
    gemm_mfma_kernel<<<ggrid, 256, 0, stream>>>(Afh, Afl, Bth, Btl, featb, N);
    eler_kernel<<<ngrid4, 256, 0, stream>>>(featb, al1, ar1, el, er, N);
    // agg1 writes layer-1 output split directly into Afh/Afl (GEMM1 already consumed them)
    agg_fused_kernel<<<ngrid4, 256, 0, stream>>>(featb, el, er, rowptr, srcs,
                                                 nullptr, nullptr, nullptr, Afh, Afl, N);

    // ---- layer 2 (residual = layer-1 output, reconstructed hi+lo) ----
    bconv_kernel<<<16, 256, 0, stream>>>(W2, Bth, Btl);
    gemm_mfma_kernel<<<ggrid, 256, 0, stream>>>(Afh, Afl, Bth, Btl, featb, N);
    eler_kernel<<<ngrid4, 256, 0, stream>>>(featb, al2, ar2, el, er, N);
    agg_fused_kernel<<<ngrid4, 256, 0, stream>>>(featb, el, er, rowptr, srcs,
                                                 Afh, Afl, out, nullptr, nullptr, N);
}